// Round 6
// baseline (267.079 us; speedup 1.0000x reference)
//
#include <hip/hip_runtime.h>
#include <math.h>

#define NB 4096
#define ND 512
#define K2 1024
#define NT8 8  // K2 / 128 K-tiles

typedef __attribute__((ext_vector_type(4))) float f32x4;
typedef __attribute__((ext_vector_type(4))) int i32x4;
typedef __attribute__((ext_vector_type(8))) int i32x8;

__device__ __forceinline__ float wave_sum(float v) {
#pragma unroll
  for (int o = 32; o > 0; o >>= 1) v += __shfl_xor(v, o);
  return v;
}

// ---------------------------------------------------------------------------
// Kernel 1: build A=[v_mean|v_sigma], B=[t_mean|t_sigma] in fp8 e4m3
// (4096x1024, 1 B/elem), plus exact f32 row square-norms
// a_sq[i] = Σ mean² + Σ var (σ²=var). Blocks 0..4095 A-side, 4096..8191 B.
// ---------------------------------------------------------------------------
__global__ __launch_bounds__(256) void prep_kernel(
    const float* __restrict__ v_mean, const float* __restrict__ v_var,
    const float* __restrict__ t_mean, const float* __restrict__ t_var,
    unsigned char* __restrict__ Afp, unsigned char* __restrict__ Bfp,
    float* __restrict__ a_sq, float* __restrict__ b_sq) {
  int b = blockIdx.x;
  int side = b >> 12;
  int row = b & (NB - 1);
  const float* mean = side ? t_mean : v_mean;
  const float* var = side ? t_var : v_var;
  unsigned char* dst = side ? Bfp : Afp;
  float* sq = side ? b_sq : a_sq;
  int t = threadIdx.x;
  float2 m2 = *(const float2*)(mean + (size_t)row * ND + 2 * t);
  float2 v2 = *(const float2*)(var + (size_t)row * ND + 2 * t);
  float s0 = sqrtf(v2.x), s1 = sqrtf(v2.y);
  int pm = __builtin_amdgcn_cvt_pk_fp8_f32(m2.x, m2.y, 0, false);
  int ps = __builtin_amdgcn_cvt_pk_fp8_f32(s0, s1, 0, false);
  *(unsigned short*)(dst + (size_t)row * K2 + 2 * t) = (unsigned short)(pm & 0xFFFF);
  *(unsigned short*)(dst + (size_t)row * K2 + ND + 2 * t) = (unsigned short)(ps & 0xFFFF);
  float p = m2.x * m2.x + m2.y * m2.y + v2.x + v2.y;
  p = wave_sum(p);
  __shared__ float sm[4];
  if ((t & 63) == 0) sm[t >> 6] = p;
  __syncthreads();
  if (t == 0) sq[row] = (sm[0] + sm[1]) + (sm[2] + sm[3]);
}

// ---------------------------------------------------------------------------
// Kernel 2: 128x256-tile fp8 MFMA GEMM via mfma_scale_f32_16x16x128_f8f6f4
// with unit scales (E8M0 127 = x1.0) -> plain fp8 GEMM at 2x bf16 rate.
// BK=128 (8 K-tiles), 8 waves (2Mx4N, wave=64x64), SINGLE-buffered LDS
// (48 KiB) so 2 blocks/CU co-reside (TLP overlap, m114). VGPR capped at 128
// via __launch_bounds__(512,4) + split B-frag halves.
// LDS rows are 128 B (128 fp8) — byte-identical swizzle geometry to the
// verified bf16 BK=64 version: phys_byte = logical ^ ((row&7)<<4), staged
// with inverse-swizzled global source (rule #21), conflict-free per 8-lane
// b128 groups.
// Fused online-LSE partials in the epilogue:
//   rowM/rowS[row][64]  ch = bn*4+wc    colM/colS[col][64]  ch = bm*2+wr
// ---------------------------------------------------------------------------
__global__ __launch_bounds__(512, 4) void gemm_fused_kernel(
    const unsigned char* __restrict__ Afp, const unsigned char* __restrict__ Bfp,
    const float* __restrict__ a_sq, const float* __restrict__ b_sq,
    const float* __restrict__ log_temp,
    float* __restrict__ rowM, float* __restrict__ rowS,
    float* __restrict__ colM, float* __restrict__ colS,
    float* __restrict__ diag) {
  __shared__ unsigned char ldsA[128 * 128];  // 16 KB
  __shared__ unsigned char ldsB[256 * 128];  // 32 KB
  int bid = blockIdx.x;
  // XCD-aware swizzle: 512 blocks, 8 XCDs -> 64 contiguous per XCD (bijective).
  int swz = (bid & 7) * 64 + (bid >> 3);
  int bm = swz >> 4, bn = swz & 15;  // 32 x 16 grid
  int brow = bm * 128, bcol = bn * 256;
  int tid = threadIdx.x;
  int lane = tid & 63, wid = tid >> 6;
  int wr = wid >> 2, wc = wid & 3;  // 2x4 wave grid, wave = 64x64
  int lr = lane & 15, lk = lane >> 4;

  // Staging: 6 x 16B loads/thread per K-tile (A 2, B 4); addresses recomputed
  // per call (saves persistent VGPRs). LDS dest = wave-uniform base + lane*16.
  int rbase = tid >> 3, chunk = tid & 7;

#define STAGE(T)                                                               \
  {                                                                            \
    _Pragma("unroll") for (int s = 0; s < 2; ++s) {                            \
      int row = s * 64 + rbase;                                                \
      __builtin_amdgcn_global_load_lds(                                        \
          (const __attribute__((address_space(1))) unsigned int*)(Afp +        \
              (size_t)(brow + row) * K2 + (T) * 128 +                          \
              ((chunk * 16) ^ ((row & 7) << 4))),                              \
          (__attribute__((address_space(3))) unsigned int*)(ldsA + row * 128 + \
              chunk * 16),                                                     \
          16, 0, 0);                                                           \
    }                                                                          \
    _Pragma("unroll") for (int s = 0; s < 4; ++s) {                            \
      int row = s * 64 + rbase;                                                \
      __builtin_amdgcn_global_load_lds(                                        \
          (const __attribute__((address_space(1))) unsigned int*)(Bfp +        \
              (size_t)(bcol + row) * K2 + (T) * 128 +                          \
              ((chunk * 16) ^ ((row & 7) << 4))),                              \
          (__attribute__((address_space(3))) unsigned int*)(ldsB + row * 128 + \
              chunk * 16),                                                     \
          16, 0, 0);                                                           \
    }                                                                          \
  }

  // Per-lane fragment addresses (byte offsets; second b128 swizzles separately).
  int sw = (lr & 7) << 4;
  int qA = lk * 32;  // this lane's 32-elem k-block within the 128-B row
  unsigned aLo = (unsigned)(wr * 64 + lr) * 128 + ((qA) ^ sw);
  unsigned aHi = (unsigned)(wr * 64 + lr) * 128 + ((qA + 16) ^ sw);
  unsigned bLo = (unsigned)(wc * 64 + lr) * 128 + ((qA) ^ sw);
  unsigned bHi = (unsigned)(wc * 64 + lr) * 128 + ((qA + 16) ^ sw);

#define LD_FRAG(base, off)                                                     \
  __builtin_shufflevector(                                                     \
      *(const i32x4*)((const char*)(base) + (off##Lo) + 0),                    \
      *(const i32x4*)((const char*)(base) + (off##Hi) + 0), 0, 1, 2, 3, 4, 5, 6, 7)

  f32x4 acc[4][4] = {};

  STAGE(0);
  asm volatile("s_waitcnt vmcnt(0)" ::: "memory");
  __builtin_amdgcn_s_barrier();

  for (int t = 0; t < NT8; ++t) {
    i32x8 af[4], bfr[2];
    // A frags (8 ds_read_b128)
#pragma unroll
    for (int mi = 0; mi < 4; ++mi) {
      i32x4 lo = *(const i32x4*)((const char*)ldsA + aLo + mi * 2048);
      i32x4 hi = *(const i32x4*)((const char*)ldsA + aHi + mi * 2048);
      af[mi] = __builtin_shufflevector(lo, hi, 0, 1, 2, 3, 4, 5, 6, 7);
    }
    // B half 0 (ni 0,1) + 8 MFMA
#pragma unroll
    for (int ni = 0; ni < 2; ++ni) {
      i32x4 lo = *(const i32x4*)((const char*)ldsB + bLo + ni * 2048);
      i32x4 hi = *(const i32x4*)((const char*)ldsB + bHi + ni * 2048);
      bfr[ni] = __builtin_shufflevector(lo, hi, 0, 1, 2, 3, 4, 5, 6, 7);
    }
    __builtin_amdgcn_s_setprio(1);
#pragma unroll
    for (int mi = 0; mi < 4; ++mi)
#pragma unroll
      for (int ni = 0; ni < 2; ++ni)
        acc[mi][ni] = __builtin_amdgcn_mfma_scale_f32_16x16x128_f8f6f4(
            af[mi], bfr[ni], acc[mi][ni], 0, 0, 0, 127, 0, 127);
    __builtin_amdgcn_s_setprio(0);
    // B half 1 (ni 2,3)
    i32x8 bfr2[2];
#pragma unroll
    for (int ni = 0; ni < 2; ++ni) {
      i32x4 lo = *(const i32x4*)((const char*)ldsB + bLo + (2 + ni) * 2048);
      i32x4 hi = *(const i32x4*)((const char*)ldsB + bHi + (2 + ni) * 2048);
      bfr2[ni] = __builtin_shufflevector(lo, hi, 0, 1, 2, 3, 4, 5, 6, 7);
    }
    // All this tile's LDS reads done -> restage same buffer for t+1.
    asm volatile("s_waitcnt lgkmcnt(0)" ::: "memory");
    __builtin_amdgcn_s_barrier();
    if (t + 1 < NT8) STAGE(t + 1);
    __builtin_amdgcn_s_setprio(1);
#pragma unroll
    for (int mi = 0; mi < 4; ++mi)
#pragma unroll
      for (int ni = 0; ni < 2; ++ni)
        acc[mi][2 + ni] = __builtin_amdgcn_mfma_scale_f32_16x16x128_f8f6f4(
            af[mi], bfr2[ni], acc[mi][2 + ni], 0, 0, 0, 127, 0, 127);
    __builtin_amdgcn_s_setprio(0);
    asm volatile("s_waitcnt vmcnt(0)" ::: "memory");
    __builtin_amdgcn_s_barrier();
  }

  // ---- epilogue: logits in-place, diag, fused online-LSE partials ----
  // C/D layout (shape-determined, dtype-independent): col=lane&15,
  // row=(lane>>4)*4+reg — identical to the bf16 16x16 family.
  float temp = fminf(expf(log_temp[0]), 100.0f);
#pragma unroll
  for (int m = 0; m < 4; ++m) {
#pragma unroll
    for (int r = 0; r < 4; ++r) {
      float asq = a_sq[brow + wr * 64 + m * 16 + lk * 4 + r];
#pragma unroll
      for (int n = 0; n < 4; ++n) {
        float bsq = b_sq[bcol + wc * 64 + n * 16 + lr];
        acc[m][n][r] = -temp * (asq + bsq - 2.0f * acc[m][n][r]);
      }
    }
  }
  // Diagonal: block contains global diag iff (bm>>1)==bn.
  if ((bm >> 1) == bn) {
#pragma unroll
    for (int m = 0; m < 4; ++m)
#pragma unroll
      for (int n = 0; n < 4; ++n)
#pragma unroll
        for (int r = 0; r < 4; ++r) {
          int rl = wr * 64 + m * 16 + lk * 4 + r;
          int cl = wc * 64 + n * 16 + lr;
          if (brow + rl == bcol + cl) diag[brow + rl] = acc[m][n][r];
        }
  }
  // Row partials: per (m,r): 4 in-lane + reduce across lr (16 lanes).
#pragma unroll
  for (int m = 0; m < 4; ++m) {
#pragma unroll
    for (int r = 0; r < 4; ++r) {
      float mx = fmaxf(fmaxf(acc[m][0][r], acc[m][1][r]),
                       fmaxf(acc[m][2][r], acc[m][3][r]));
#pragma unroll
      for (int o = 1; o < 16; o <<= 1) mx = fmaxf(mx, __shfl_xor(mx, o));
      float s = __expf(acc[m][0][r] - mx) + __expf(acc[m][1][r] - mx) +
                __expf(acc[m][2][r] - mx) + __expf(acc[m][3][r] - mx);
#pragma unroll
      for (int o = 1; o < 16; o <<= 1) s += __shfl_xor(s, o);
      if (lr == 0) {
        int row = brow + wr * 64 + m * 16 + lk * 4 + r;
        int ch = bn * 4 + wc;
        rowM[(size_t)row * 64 + ch] = mx;
        rowS[(size_t)row * 64 + ch] = s;
      }
    }
  }
  // Col partials: per n: 16 in-lane (m,r) + full lk reduce (xor16, xor32).
#pragma unroll
  for (int n = 0; n < 4; ++n) {
    float mx = -INFINITY;
#pragma unroll
    for (int m = 0; m < 4; ++m)
#pragma unroll
      for (int r = 0; r < 4; ++r) mx = fmaxf(mx, acc[m][n][r]);
    mx = fmaxf(mx, __shfl_xor(mx, 16));
    mx = fmaxf(mx, __shfl_xor(mx, 32));
    float s = 0.f;
#pragma unroll
    for (int m = 0; m < 4; ++m)
#pragma unroll
      for (int r = 0; r < 4; ++r) s += __expf(acc[m][n][r] - mx);
    s += __shfl_xor(s, 16);
    s += __shfl_xor(s, 32);
    if (lk == 0) {
      int col = bcol + wc * 64 + n * 16 + lr;
      int ch = bm * 2 + wr;
      colM[(size_t)col * 64 + ch] = mx;
      colS[(size_t)col * 64 + ch] = s;
    }
  }
}

// ---------------------------------------------------------------------------
// Kernel 3: combine 64 chunk-partials per row/col -> (lse - diag).
// ---------------------------------------------------------------------------
__global__ __launch_bounds__(256) void combine_kernel(
    const float* __restrict__ rowM, const float* __restrict__ rowS,
    const float* __restrict__ colM, const float* __restrict__ colS,
    const float* __restrict__ diag, float* __restrict__ hrow,
    float* __restrict__ hcol) {
  int b = blockIdx.x;
  int t = threadIdx.x;
  int wave = t >> 6, lane = t & 63;
  int isCol = b >> 10;
  int idx = (b & 1023) * 4 + wave;
  const float* PM = isCol ? colM : rowM;
  const float* PS = isCol ? colS : rowS;
  float M = PM[(size_t)idx * 64 + lane];
  float S = PS[(size_t)idx * 64 + lane];
#pragma unroll
  for (int o = 1; o < 64; o <<= 1) {
    float M2 = __shfl_xor(M, o), S2 = __shfl_xor(S, o);
    float nM = fmaxf(M, M2);
    S = S * __expf(M - nM) + S2 * __expf(M2 - nM);
    M = nM;
  }
  if (lane == 0) {
    float v = M + logf(S) - diag[idx];
    (isCol ? hcol : hrow)[idx] = v;
  }
}

// Kernel 4: final mean in f64: 0.5*(mean(hrow) + mean(hcol)).
__global__ __launch_bounds__(256) void final_kernel(
    const float* __restrict__ hrow, const float* __restrict__ hcol,
    float* __restrict__ out) {
  int t = threadIdx.x;
  double a = 0.0;
  for (int i = t; i < NB; i += 256) {
    a += 0.5 * ((double)hrow[i] + (double)hcol[i]);
  }
#pragma unroll
  for (int o = 32; o > 0; o >>= 1) a += __shfl_xor(a, o);
  __shared__ double sd[4];
  if ((t & 63) == 0) sd[t >> 6] = a;
  __syncthreads();
  if (t == 0) out[0] = (float)(((sd[0] + sd[1]) + (sd[2] + sd[3])) / (double)NB);
}

extern "C" void kernel_launch(void* const* d_in, const int* in_sizes, int n_in,
                              void* d_out, int out_size, void* d_ws, size_t ws_size,
                              hipStream_t stream) {
  const float* v_mean = (const float*)d_in[0];
  const float* v_var = (const float*)d_in[1];
  const float* t_mean = (const float*)d_in[2];
  const float* t_var = (const float*)d_in[3];
  const float* log_temp = (const float*)d_in[4];
  float* out = (float*)d_out;

  char* ws = (char*)d_ws;
  unsigned char* Afp = (unsigned char*)ws;                       // 4 MiB
  unsigned char* Bfp = (unsigned char*)(ws + 4194304);           // 4 MiB
  float* rowM = (float*)(ws + 8388608);                          // 1 MiB each
  float* rowS = rowM + (size_t)NB * 64;
  float* colM = rowS + (size_t)NB * 64;
  float* colS = colM + (size_t)NB * 64;
  float* diag = colS + (size_t)NB * 64;                          // 16 KiB each
  float* hrow = diag + NB;
  float* hcol = hrow + NB;
  float* a_sq = hcol + NB;
  float* b_sq = a_sq + NB;

  prep_kernel<<<8192, 256, 0, stream>>>(v_mean, v_var, t_mean, t_var, Afp, Bfp, a_sq, b_sq);
  gemm_fused_kernel<<<512, 512, 0, stream>>>(Afp, Bfp, a_sq, b_sq, log_temp,
                                             rowM, rowS, colM, colS, diag);
  combine_kernel<<<2048, 256, 0, stream>>>(rowM, rowS, colM, colS, diag, hrow, hcol);
  final_kernel<<<1, 256, 0, stream>>>(hrow, hcol, out);
}

// Round 7
// 158.875 us; speedup vs baseline: 1.6811x; 1.6811x over previous
//
#include <hip/hip_runtime.h>
#include <math.h>

#define NB 4096
#define ND 512
#define K2 1024
#define NT8 8  // K2 / 128 K-tiles

typedef __attribute__((ext_vector_type(4))) float f32x4;
typedef __attribute__((ext_vector_type(16))) float f32x16;
typedef __attribute__((ext_vector_type(8))) int i32x8;

__device__ __forceinline__ float wave_sum(float v) {
#pragma unroll
  for (int o = 32; o > 0; o >>= 1) v += __shfl_xor(v, o);
  return v;
}

// ---------------------------------------------------------------------------
// Kernel 1: build A=[v_mean|v_sigma], B=[t_mean|t_sigma] in fp8 e4m3
// (4096x1024, 1 B/elem), plus exact f32 row square-norms
// a_sq[i] = Σ mean² + Σ var (σ²=var). Blocks 0..4095 A-side, 4096..8191 B.
// ---------------------------------------------------------------------------
__global__ __launch_bounds__(256) void prep_kernel(
    const float* __restrict__ v_mean, const float* __restrict__ v_var,
    const float* __restrict__ t_mean, const float* __restrict__ t_var,
    unsigned char* __restrict__ Afp, unsigned char* __restrict__ Bfp,
    float* __restrict__ a_sq, float* __restrict__ b_sq) {
  int b = blockIdx.x;
  int side = b >> 12;
  int row = b & (NB - 1);
  const float* mean = side ? t_mean : v_mean;
  const float* var = side ? t_var : v_var;
  unsigned char* dst = side ? Bfp : Afp;
  float* sq = side ? b_sq : a_sq;
  int t = threadIdx.x;
  float2 m2 = *(const float2*)(mean + (size_t)row * ND + 2 * t);
  float2 v2 = *(const float2*)(var + (size_t)row * ND + 2 * t);
  float s0 = sqrtf(v2.x), s1 = sqrtf(v2.y);
  int pm = __builtin_amdgcn_cvt_pk_fp8_f32(m2.x, m2.y, 0, false);
  int ps = __builtin_amdgcn_cvt_pk_fp8_f32(s0, s1, 0, false);
  *(unsigned short*)(dst + (size_t)row * K2 + 2 * t) = (unsigned short)(pm & 0xFFFF);
  *(unsigned short*)(dst + (size_t)row * K2 + ND + 2 * t) = (unsigned short)(ps & 0xFFFF);
  float p = m2.x * m2.x + m2.y * m2.y + v2.x + v2.y;
  p = wave_sum(p);
  __shared__ float sm[4];
  if ((t & 63) == 0) sm[t >> 6] = p;
  __syncthreads();
  if (t == 0) sq[row] = (sm[0] + sm[1]) + (sm[2] + sm[3]);
}

// ---------------------------------------------------------------------------
// Kernel 2: 128x256-tile fp8 GEMM via mfma_scale_f32_32x32x64_f8f6f4 with
// unit scales (E8M0 127 = x1.0). BK=128 (8 staged tiles, 2 k-steps each),
// 8 waves (2Mx4N, wave = 64x64 = 2x2 of 32x32), SINGLE-buffered LDS (48 KiB)
// so 2 blocks/CU co-reside (TLP overlap, m114). __launch_bounds__(512,4).
//
// LDS swizzle is 32B-GRANULAR: phys_byte = logical ^ ((row&3)<<5). Each MFMA
// operand (32 contiguous fp8) stays contiguous -> direct i32x8 load (2
// adjacent ds_read_b128, no shufflevector, no transient double-liveness).
// Staged with inverse-swizzled global source (rule #21).
// Fused online-LSE partials in the epilogue:
//   rowM/rowS[row][64]  ch = bn*4+wc    colM/colS[col][64]  ch = bm*2+wr
// ---------------------------------------------------------------------------
__global__ __launch_bounds__(512, 4) void gemm_fused_kernel(
    const unsigned char* __restrict__ Afp, const unsigned char* __restrict__ Bfp,
    const float* __restrict__ a_sq, const float* __restrict__ b_sq,
    const float* __restrict__ log_temp,
    float* __restrict__ rowM, float* __restrict__ rowS,
    float* __restrict__ colM, float* __restrict__ colS,
    float* __restrict__ diag) {
  __shared__ unsigned char ldsA[128 * 128];  // 16 KB
  __shared__ unsigned char ldsB[256 * 128];  // 32 KB
  int bid = blockIdx.x;
  // XCD-aware swizzle: 512 blocks, 8 XCDs -> 64 contiguous per XCD (bijective).
  int swz = (bid & 7) * 64 + (bid >> 3);
  int bm = swz >> 4, bn = swz & 15;  // 32 x 16 grid
  int brow = bm * 128, bcol = bn * 256;
  int tid = threadIdx.x;
  int lane = tid & 63, wid = tid >> 6;
  int wr = wid >> 2, wc = wid & 3;  // 2x4 wave grid, wave = 64x64
  int l31 = lane & 31, kh = lane >> 5;

  int rbase = tid >> 3, chunk = tid & 7;

#define STAGE(T)                                                               \
  {                                                                            \
    _Pragma("unroll") for (int s = 0; s < 2; ++s) {                            \
      int row = s * 64 + rbase;                                                \
      __builtin_amdgcn_global_load_lds(                                        \
          (const __attribute__((address_space(1))) unsigned int*)(Afp +        \
              (size_t)(brow + row) * K2 + (T) * 128 +                          \
              ((chunk * 16) ^ ((row & 3) << 5))),                              \
          (__attribute__((address_space(3))) unsigned int*)(ldsA + row * 128 + \
              chunk * 16),                                                     \
          16, 0, 0);                                                           \
    }                                                                          \
    _Pragma("unroll") for (int s = 0; s < 4; ++s) {                            \
      int row = s * 64 + rbase;                                                \
      __builtin_amdgcn_global_load_lds(                                        \
          (const __attribute__((address_space(1))) unsigned int*)(Bfp +        \
              (size_t)(bcol + row) * K2 + (T) * 128 +                          \
              ((chunk * 16) ^ ((row & 3) << 5))),                              \
          (__attribute__((address_space(3))) unsigned int*)(ldsB + row * 128 + \
              chunk * 16),                                                     \
          16, 0, 0);                                                           \
    }                                                                          \
  }

  // Per-lane fragment byte offsets. MFMA 32x32 A/B layout: row = lane&31,
  // k = (lane>>5)*32 + j (32 contiguous). Swizzle s depends only on row&3 =
  // lane&3 (tile offsets are multiples of 32). k-step 1 address = k-step 0 ^ 64.
  unsigned sws = (unsigned)(lane & 3) << 5;
  unsigned aOff[2], bOff[2];
#pragma unroll
  for (int mi = 0; mi < 2; ++mi)
    aOff[mi] = (unsigned)(wr * 64 + mi * 32 + l31) * 128 + (((unsigned)kh * 32) ^ sws);
#pragma unroll
  for (int ni = 0; ni < 2; ++ni)
    bOff[ni] = (unsigned)(wc * 64 + ni * 32 + l31) * 128 + (((unsigned)kh * 32) ^ sws);

  f32x16 acc[2][2] = {};

  STAGE(0);
  asm volatile("s_waitcnt vmcnt(0)" ::: "memory");
  __builtin_amdgcn_s_barrier();

  for (int t = 0; t < NT8; ++t) {
    // k-step 0: 6 x (2 ds_read_b128) direct i32x8 loads, then 4 MFMA.
    i32x8 fa0 = *(const i32x8*)(ldsA + aOff[0]);
    i32x8 fa1 = *(const i32x8*)(ldsA + aOff[1]);
    i32x8 fb0 = *(const i32x8*)(ldsB + bOff[0]);
    i32x8 fb1 = *(const i32x8*)(ldsB + bOff[1]);
    __builtin_amdgcn_s_setprio(1);
    acc[0][0] = __builtin_amdgcn_mfma_scale_f32_32x32x64_f8f6f4(
        fa0, fb0, acc[0][0], 0, 0, 0, 127, 0, 127);
    acc[0][1] = __builtin_amdgcn_mfma_scale_f32_32x32x64_f8f6f4(
        fa0, fb1, acc[0][1], 0, 0, 0, 127, 0, 127);
    acc[1][0] = __builtin_amdgcn_mfma_scale_f32_32x32x64_f8f6f4(
        fa1, fb0, acc[1][0], 0, 0, 0, 127, 0, 127);
    acc[1][1] = __builtin_amdgcn_mfma_scale_f32_32x32x64_f8f6f4(
        fa1, fb1, acc[1][1], 0, 0, 0, 127, 0, 127);
    __builtin_amdgcn_s_setprio(0);
    // k-step 1 (addresses ^64), reuse registers.
    i32x8 ga0 = *(const i32x8*)(ldsA + (aOff[0] ^ 64u));
    i32x8 ga1 = *(const i32x8*)(ldsA + (aOff[1] ^ 64u));
    i32x8 gb0 = *(const i32x8*)(ldsB + (bOff[0] ^ 64u));
    i32x8 gb1 = *(const i32x8*)(ldsB + (bOff[1] ^ 64u));
    // All this tile's LDS reads drained -> safe to restage the buffer.
    asm volatile("s_waitcnt lgkmcnt(0)" ::: "memory");
    __builtin_amdgcn_s_barrier();
    if (t + 1 < NT8) STAGE(t + 1);
    __builtin_amdgcn_s_setprio(1);
    acc[0][0] = __builtin_amdgcn_mfma_scale_f32_32x32x64_f8f6f4(
        ga0, gb0, acc[0][0], 0, 0, 0, 127, 0, 127);
    acc[0][1] = __builtin_amdgcn_mfma_scale_f32_32x32x64_f8f6f4(
        ga0, gb1, acc[0][1], 0, 0, 0, 127, 0, 127);
    acc[1][0] = __builtin_amdgcn_mfma_scale_f32_32x32x64_f8f6f4(
        ga1, gb0, acc[1][0], 0, 0, 0, 127, 0, 127);
    acc[1][1] = __builtin_amdgcn_mfma_scale_f32_32x32x64_f8f6f4(
        ga1, gb1, acc[1][1], 0, 0, 0, 127, 0, 127);
    __builtin_amdgcn_s_setprio(0);
    asm volatile("s_waitcnt vmcnt(0)" ::: "memory");
    __builtin_amdgcn_s_barrier();
  }

  // ---- epilogue: logits in-place, diag, fused online-LSE partials ----
  // 32x32 C/D layout (m74/m101, dtype-independent):
  //   col = lane&31, row = (reg&3) + 8*(reg>>2) + 4*(lane>>5).
  float temp = fminf(expf(log_temp[0]), 100.0f);
#pragma unroll
  for (int mi = 0; mi < 2; ++mi) {
#pragma unroll
    for (int reg = 0; reg < 16; ++reg) {
      int rl = wr * 64 + mi * 32 + (reg & 3) + 8 * (reg >> 2) + 4 * kh;
      float asq = a_sq[brow + rl];
#pragma unroll
      for (int ni = 0; ni < 2; ++ni) {
        float bsq = b_sq[bcol + wc * 64 + ni * 32 + l31];
        acc[mi][ni][reg] = -temp * (asq + bsq - 2.0f * acc[mi][ni][reg]);
      }
    }
  }
  // Diagonal: block contains global diag iff (bm>>1)==bn.
  if ((bm >> 1) == bn) {
#pragma unroll
    for (int mi = 0; mi < 2; ++mi)
#pragma unroll
      for (int ni = 0; ni < 2; ++ni)
#pragma unroll
        for (int reg = 0; reg < 16; ++reg) {
          int rl = wr * 64 + mi * 32 + (reg & 3) + 8 * (reg >> 2) + 4 * kh;
          int cl = wc * 64 + ni * 32 + l31;
          if (brow + rl == bcol + cl) diag[brow + rl] = acc[mi][ni][reg];
        }
  }
  // Row partials: per (mi,reg): 2 in-lane + reduce across 32 cols (l31).
#pragma unroll
  for (int mi = 0; mi < 2; ++mi) {
#pragma unroll
    for (int reg = 0; reg < 16; ++reg) {
      float mx = fmaxf(acc[mi][0][reg], acc[mi][1][reg]);
#pragma unroll
      for (int o = 1; o < 32; o <<= 1) mx = fmaxf(mx, __shfl_xor(mx, o));
      float s = __expf(acc[mi][0][reg] - mx) + __expf(acc[mi][1][reg] - mx);
#pragma unroll
      for (int o = 1; o < 32; o <<= 1) s += __shfl_xor(s, o);
      if (l31 == 0) {
        int row = brow + wr * 64 + mi * 32 + (reg & 3) + 8 * (reg >> 2) + 4 * kh;
        int ch = bn * 4 + wc;
        rowM[(size_t)row * 64 + ch] = mx;
        rowS[(size_t)row * 64 + ch] = s;
      }
    }
  }
  // Col partials: per ni: 32 in-lane (mi,reg) + merge kh halves (xor 32).
#pragma unroll
  for (int ni = 0; ni < 2; ++ni) {
    float mx = -INFINITY;
#pragma unroll
    for (int mi = 0; mi < 2; ++mi)
#pragma unroll
      for (int reg = 0; reg < 16; ++reg) mx = fmaxf(mx, acc[mi][ni][reg]);
    mx = fmaxf(mx, __shfl_xor(mx, 32));
    float s = 0.f;
#pragma unroll
    for (int mi = 0; mi < 2; ++mi)
#pragma unroll
      for (int reg = 0; reg < 16; ++reg) s += __expf(acc[mi][ni][reg] - mx);
    s += __shfl_xor(s, 32);
    if (kh == 0) {
      int col = bcol + wc * 64 + ni * 32 + l31;
      int ch = bm * 2 + wr;
      colM[(size_t)col * 64 + ch] = mx;
      colS[(size_t)col * 64 + ch] = s;
    }
  }
}

// ---------------------------------------------------------------------------
// Kernel 3: combine 64 chunk-partials per row/col -> (lse - diag).
// ---------------------------------------------------------------------------
__global__ __launch_bounds__(256) void combine_kernel(
    const float* __restrict__ rowM, const float* __restrict__ rowS,
    const float* __restrict__ colM, const float* __restrict__ colS,
    const float* __restrict__ diag, float* __restrict__ hrow,
    float* __restrict__ hcol) {
  int b = blockIdx.x;
  int t = threadIdx.x;
  int wave = t >> 6, lane = t & 63;
  int isCol = b >> 10;
  int idx = (b & 1023) * 4 + wave;
  const float* PM = isCol ? colM : rowM;
  const float* PS = isCol ? colS : rowS;
  float M = PM[(size_t)idx * 64 + lane];
  float S = PS[(size_t)idx * 64 + lane];
#pragma unroll
  for (int o = 1; o < 64; o <<= 1) {
    float M2 = __shfl_xor(M, o), S2 = __shfl_xor(S, o);
    float nM = fmaxf(M, M2);
    S = S * __expf(M - nM) + S2 * __expf(M2 - nM);
    M = nM;
  }
  if (lane == 0) {
    float v = M + logf(S) - diag[idx];
    (isCol ? hcol : hrow)[idx] = v;
  }
}

// Kernel 4: final mean in f64: 0.5*(mean(hrow) + mean(hcol)).
__global__ __launch_bounds__(256) void final_kernel(
    const float* __restrict__ hrow, const float* __restrict__ hcol,
    float* __restrict__ out) {
  int t = threadIdx.x;
  double a = 0.0;
  for (int i = t; i < NB; i += 256) {
    a += 0.5 * ((double)hrow[i] + (double)hcol[i]);
  }
#pragma unroll
  for (int o = 32; o > 0; o >>= 1) a += __shfl_xor(a, o);
  __shared__ double sd[4];
  if ((t & 63) == 0) sd[t >> 6] = a;
  __syncthreads();
  if (t == 0) out[0] = (float)(((sd[0] + sd[1]) + (sd[2] + sd[3])) / (double)NB);
}

extern "C" void kernel_launch(void* const* d_in, const int* in_sizes, int n_in,
                              void* d_out, int out_size, void* d_ws, size_t ws_size,
                              hipStream_t stream) {
  const float* v_mean = (const float*)d_in[0];
  const float* v_var = (const float*)d_in[1];
  const float* t_mean = (const float*)d_in[2];
  const float* t_var = (const float*)d_in[3];
  const float* log_temp = (const float*)d_in[4];
  float* out = (float*)d_out;

  char* ws = (char*)d_ws;
  unsigned char* Afp = (unsigned char*)ws;                       // 4 MiB
  unsigned char* Bfp = (unsigned char*)(ws + 4194304);           // 4 MiB
  float* rowM = (float*)(ws + 8388608);                          // 1 MiB each
  float* rowS = rowM + (size_t)NB * 64;
  float* colM = rowS + (size_t)NB * 64;
  float* colS = colM + (size_t)NB * 64;
  float* diag = colS + (size_t)NB * 64;                          // 16 KiB each
  float* hrow = diag + NB;
  float* hcol = hrow + NB;
  float* a_sq = hcol + NB;
  float* b_sq = a_sq + NB;

  prep_kernel<<<8192, 256, 0, stream>>>(v_mean, v_var, t_mean, t_var, Afp, Bfp, a_sq, b_sq);
  gemm_fused_kernel<<<512, 512, 0, stream>>>(Afp, Bfp, a_sq, b_sq, log_temp,
                                             rowM, rowS, colM, colS, diag);
  combine_kernel<<<2048, 256, 0, stream>>>(rowM, rowS, colM, colS, diag, hrow, hcol);
  final_kernel<<<1, 256, 0, stream>>>(hrow, hcol, out);
}

// Round 8
// 100.916 us; speedup vs baseline: 2.6465x; 1.5743x over previous
//
#include <hip/hip_runtime.h>
#include <math.h>

#define NB 4096
#define ND 512
#define K2 1024
#define NT8 8  // K2 / 128 K-tiles

typedef __attribute__((ext_vector_type(4))) float f32x4;
typedef __attribute__((ext_vector_type(16))) float f32x16;
typedef __attribute__((ext_vector_type(8))) int i32x8;

__device__ __forceinline__ float wave_sum(float v) {
#pragma unroll
  for (int o = 32; o > 0; o >>= 1) v += __shfl_xor(v, o);
  return v;
}

// ---------------------------------------------------------------------------
// Kernel 1: build A=[v_mean|v_sigma], B=[t_mean|t_sigma] in fp8 e4m3
// (4096x1024, 1 B/elem), plus exact f32 row square-norms
// a_sq[i] = Σ mean² + Σ var (σ²=var). Blocks 0..4095 A-side, 4096..8191 B.
// ---------------------------------------------------------------------------
__global__ __launch_bounds__(256) void prep_kernel(
    const float* __restrict__ v_mean, const float* __restrict__ v_var,
    const float* __restrict__ t_mean, const float* __restrict__ t_var,
    unsigned char* __restrict__ Afp, unsigned char* __restrict__ Bfp,
    float* __restrict__ a_sq, float* __restrict__ b_sq) {
  int b = blockIdx.x;
  int side = b >> 12;
  int row = b & (NB - 1);
  const float* mean = side ? t_mean : v_mean;
  const float* var = side ? t_var : v_var;
  unsigned char* dst = side ? Bfp : Afp;
  float* sq = side ? b_sq : a_sq;
  int t = threadIdx.x;
  float2 m2 = *(const float2*)(mean + (size_t)row * ND + 2 * t);
  float2 v2 = *(const float2*)(var + (size_t)row * ND + 2 * t);
  float s0 = sqrtf(v2.x), s1 = sqrtf(v2.y);
  int pm = __builtin_amdgcn_cvt_pk_fp8_f32(m2.x, m2.y, 0, false);
  int ps = __builtin_amdgcn_cvt_pk_fp8_f32(s0, s1, 0, false);
  *(unsigned short*)(dst + (size_t)row * K2 + 2 * t) = (unsigned short)(pm & 0xFFFF);
  *(unsigned short*)(dst + (size_t)row * K2 + ND + 2 * t) = (unsigned short)(ps & 0xFFFF);
  float p = m2.x * m2.x + m2.y * m2.y + v2.x + v2.y;
  p = wave_sum(p);
  __shared__ float sm[4];
  if ((t & 63) == 0) sm[t >> 6] = p;
  __syncthreads();
  if (t == 0) sq[row] = (sm[0] + sm[1]) + (sm[2] + sm[3]);
}

// ---------------------------------------------------------------------------
// Kernel 2: 128x256-tile fp8 GEMM via mfma_scale_f32_32x32x64_f8f6f4 with
// unit scales (E8M0 127 = x1.0). BK=128, DOUBLE-buffered LDS (96 KiB),
// 8 waves (2Mx4N, wave = 64x64 = 2x2 of 32x32). __launch_bounds__(512,2):
// 256-reg cap so acc(64) + frag peak(64) + misc fits with ZERO spill
// (R7 lesson: the 128-cap forced 270 MB of scratch traffic).
// One barrier per K-tile: STAGE(t+1 -> other buf) issued at tile start,
// its latency hides under 12 ds_read_b128 + 8 MFMA of tile t.
//
// LDS swizzle is 32B-granular: phys_byte = logical ^ ((row&3)<<5). Operands
// (32 contiguous fp8) stay contiguous -> direct i32x8 load (2 adjacent
// ds_read_b128); residual 2-way bank conflicts are ~free (m136). Staged with
// inverse-swizzled global source (rule #21).
// Fused online-LSE partials in the epilogue:
//   rowM/rowS[row][64]  ch = bn*4+wc    colM/colS[col][64]  ch = bm*2+wr
// ---------------------------------------------------------------------------
__global__ __launch_bounds__(512, 2) void gemm_fused_kernel(
    const unsigned char* __restrict__ Afp, const unsigned char* __restrict__ Bfp,
    const float* __restrict__ a_sq, const float* __restrict__ b_sq,
    const float* __restrict__ log_temp,
    float* __restrict__ rowM, float* __restrict__ rowS,
    float* __restrict__ colM, float* __restrict__ colS,
    float* __restrict__ diag) {
  __shared__ unsigned char ldsA[2][128 * 128];  // 2 x 16 KB
  __shared__ unsigned char ldsB[2][256 * 128];  // 2 x 32 KB
  int bid = blockIdx.x;
  // XCD-aware swizzle: 512 blocks, 8 XCDs -> 64 contiguous per XCD (bijective).
  int swz = (bid & 7) * 64 + (bid >> 3);
  int bm = swz >> 4, bn = swz & 15;  // 32 x 16 grid
  int brow = bm * 128, bcol = bn * 256;
  int tid = threadIdx.x;
  int lane = tid & 63, wid = tid >> 6;
  int wr = wid >> 2, wc = wid & 3;  // 2x4 wave grid, wave = 64x64
  int l31 = lane & 31, kh = lane >> 5;

  // Precomputed staging offsets (6 loads/thread): global byte offsets with
  // inverse swizzle, and linear LDS byte offsets.
  int rbase = tid >> 3, chunk = tid & 7;
  unsigned gA[2], gB[4];
  int ldA[2], ldB[4];
#pragma unroll
  for (int s = 0; s < 2; ++s) {
    int row = s * 64 + rbase;
    gA[s] = (unsigned)(brow + row) * K2 + ((chunk * 16) ^ ((row & 3) << 5));
    ldA[s] = row * 128 + chunk * 16;
  }
#pragma unroll
  for (int s = 0; s < 4; ++s) {
    int row = s * 64 + rbase;
    gB[s] = (unsigned)(bcol + row) * K2 + ((chunk * 16) ^ ((row & 3) << 5));
    ldB[s] = row * 128 + chunk * 16;
  }

#define STAGE(T, C)                                                            \
  {                                                                            \
    _Pragma("unroll") for (int s = 0; s < 2; ++s)                              \
        __builtin_amdgcn_global_load_lds(                                      \
            (const __attribute__((address_space(1))) unsigned int*)(Afp +      \
                gA[s] + (unsigned)(T) * 128),                                  \
            (__attribute__((address_space(3))) unsigned int*)(&ldsA[C][0] +    \
                ldA[s]),                                                       \
            16, 0, 0);                                                         \
    _Pragma("unroll") for (int s = 0; s < 4; ++s)                              \
        __builtin_amdgcn_global_load_lds(                                      \
            (const __attribute__((address_space(1))) unsigned int*)(Bfp +      \
                gB[s] + (unsigned)(T) * 128),                                  \
            (__attribute__((address_space(3))) unsigned int*)(&ldsB[C][0] +    \
                ldB[s]),                                                       \
            16, 0, 0);                                                         \
  }

  // Per-lane fragment byte offsets. MFMA 32x32 A/B layout: row = lane&31,
  // k = (lane>>5)*32 + j (32 contiguous). k-step 1 address = k-step 0 ^ 64.
  unsigned sws = (unsigned)(lane & 3) << 5;
  unsigned aOff[2], bOff[2];
#pragma unroll
  for (int mi = 0; mi < 2; ++mi)
    aOff[mi] = (unsigned)(wr * 64 + mi * 32 + l31) * 128 + (((unsigned)kh * 32) ^ sws);
#pragma unroll
  for (int ni = 0; ni < 2; ++ni)
    bOff[ni] = (unsigned)(wc * 64 + ni * 32 + l31) * 128 + (((unsigned)kh * 32) ^ sws);

  f32x16 acc[2][2] = {};

  STAGE(0, 0);
  asm volatile("s_waitcnt vmcnt(0)" ::: "memory");
  __builtin_amdgcn_s_barrier();

  for (int t = 0; t < NT8; ++t) {
    const int c = t & 1;
    const unsigned char* bufa = &ldsA[c][0];
    const unsigned char* bufb = &ldsB[c][0];
    // Issue next tile's stage into the OTHER buffer first (latency hides
    // under this tile's ds_read + MFMA).
    if (t + 1 < NT8) STAGE(t + 1, c ^ 1);
    // k-step 0 frags + 4 MFMA
    i32x8 fa0 = *(const i32x8*)(bufa + aOff[0]);
    i32x8 fa1 = *(const i32x8*)(bufa + aOff[1]);
    i32x8 fb0 = *(const i32x8*)(bufb + bOff[0]);
    i32x8 fb1 = *(const i32x8*)(bufb + bOff[1]);
    __builtin_amdgcn_s_setprio(1);
    acc[0][0] = __builtin_amdgcn_mfma_scale_f32_32x32x64_f8f6f4(
        fa0, fb0, acc[0][0], 0, 0, 0, 127, 0, 127);
    acc[0][1] = __builtin_amdgcn_mfma_scale_f32_32x32x64_f8f6f4(
        fa0, fb1, acc[0][1], 0, 0, 0, 127, 0, 127);
    acc[1][0] = __builtin_amdgcn_mfma_scale_f32_32x32x64_f8f6f4(
        fa1, fb0, acc[1][0], 0, 0, 0, 127, 0, 127);
    acc[1][1] = __builtin_amdgcn_mfma_scale_f32_32x32x64_f8f6f4(
        fa1, fb1, acc[1][1], 0, 0, 0, 127, 0, 127);
    __builtin_amdgcn_s_setprio(0);
    // k-step 1 frags (addresses ^64) + 4 MFMA
    i32x8 ga0 = *(const i32x8*)(bufa + (aOff[0] ^ 64u));
    i32x8 ga1 = *(const i32x8*)(bufa + (aOff[1] ^ 64u));
    i32x8 gb0 = *(const i32x8*)(bufb + (bOff[0] ^ 64u));
    i32x8 gb1 = *(const i32x8*)(bufb + (bOff[1] ^ 64u));
    __builtin_amdgcn_s_setprio(1);
    acc[0][0] = __builtin_amdgcn_mfma_scale_f32_32x32x64_f8f6f4(
        ga0, gb0, acc[0][0], 0, 0, 0, 127, 0, 127);
    acc[0][1] = __builtin_amdgcn_mfma_scale_f32_32x32x64_f8f6f4(
        ga0, gb1, acc[0][1], 0, 0, 0, 127, 0, 127);
    acc[1][0] = __builtin_amdgcn_mfma_scale_f32_32x32x64_f8f6f4(
        ga1, gb0, acc[1][0], 0, 0, 0, 127, 0, 127);
    acc[1][1] = __builtin_amdgcn_mfma_scale_f32_32x32x64_f8f6f4(
        ga1, gb1, acc[1][1], 0, 0, 0, 127, 0, 127);
    __builtin_amdgcn_s_setprio(0);
    // This tile's reads done (lgkm), next tile's stage landed (vm) -> barrier.
    asm volatile("s_waitcnt lgkmcnt(0)" ::: "memory");
    asm volatile("s_waitcnt vmcnt(0)" ::: "memory");
    __builtin_amdgcn_s_barrier();
  }

  // ---- epilogue: logits in-place, diag, fused online-LSE partials ----
  // 32x32 C/D layout (m74/m101, dtype-independent):
  //   col = lane&31, row = (reg&3) + 8*(reg>>2) + 4*(lane>>5).
  float temp = fminf(expf(log_temp[0]), 100.0f);
#pragma unroll
  for (int mi = 0; mi < 2; ++mi) {
#pragma unroll
    for (int reg = 0; reg < 16; ++reg) {
      int rl = wr * 64 + mi * 32 + (reg & 3) + 8 * (reg >> 2) + 4 * kh;
      float asq = a_sq[brow + rl];
#pragma unroll
      for (int ni = 0; ni < 2; ++ni) {
        float bsq = b_sq[bcol + wc * 64 + ni * 32 + l31];
        acc[mi][ni][reg] = -temp * (asq + bsq - 2.0f * acc[mi][ni][reg]);
      }
    }
  }
  // Diagonal: block contains global diag iff (bm>>1)==bn.
  if ((bm >> 1) == bn) {
#pragma unroll
    for (int mi = 0; mi < 2; ++mi)
#pragma unroll
      for (int ni = 0; ni < 2; ++ni)
#pragma unroll
        for (int reg = 0; reg < 16; ++reg) {
          int rl = wr * 64 + mi * 32 + (reg & 3) + 8 * (reg >> 2) + 4 * kh;
          int cl = wc * 64 + ni * 32 + l31;
          if (brow + rl == bcol + cl) diag[brow + rl] = acc[mi][ni][reg];
        }
  }
  // Row partials: per (mi,reg): 2 in-lane + reduce across 32 cols (l31).
#pragma unroll
  for (int mi = 0; mi < 2; ++mi) {
#pragma unroll
    for (int reg = 0; reg < 16; ++reg) {
      float mx = fmaxf(acc[mi][0][reg], acc[mi][1][reg]);
#pragma unroll
      for (int o = 1; o < 32; o <<= 1) mx = fmaxf(mx, __shfl_xor(mx, o));
      float s = __expf(acc[mi][0][reg] - mx) + __expf(acc[mi][1][reg] - mx);
#pragma unroll
      for (int o = 1; o < 32; o <<= 1) s += __shfl_xor(s, o);
      if (l31 == 0) {
        int row = brow + wr * 64 + mi * 32 + (reg & 3) + 8 * (reg >> 2) + 4 * kh;
        int ch = bn * 4 + wc;
        rowM[(size_t)row * 64 + ch] = mx;
        rowS[(size_t)row * 64 + ch] = s;
      }
    }
  }
  // Col partials: per ni: 32 in-lane (mi,reg) + merge kh halves (xor 32).
#pragma unroll
  for (int ni = 0; ni < 2; ++ni) {
    float mx = -INFINITY;
#pragma unroll
    for (int mi = 0; mi < 2; ++mi)
#pragma unroll
      for (int reg = 0; reg < 16; ++reg) mx = fmaxf(mx, acc[mi][ni][reg]);
    mx = fmaxf(mx, __shfl_xor(mx, 32));
    float s = 0.f;
#pragma unroll
    for (int mi = 0; mi < 2; ++mi)
#pragma unroll
      for (int reg = 0; reg < 16; ++reg) s += __expf(acc[mi][ni][reg] - mx);
    s += __shfl_xor(s, 32);
    if (kh == 0) {
      int col = bcol + wc * 64 + ni * 32 + l31;
      int ch = bm * 2 + wr;
      colM[(size_t)col * 64 + ch] = mx;
      colS[(size_t)col * 64 + ch] = s;
    }
  }
}

// ---------------------------------------------------------------------------
// Kernel 3: combine 64 chunk-partials per row/col -> (lse - diag).
// ---------------------------------------------------------------------------
__global__ __launch_bounds__(256) void combine_kernel(
    const float* __restrict__ rowM, const float* __restrict__ rowS,
    const float* __restrict__ colM, const float* __restrict__ colS,
    const float* __restrict__ diag, float* __restrict__ hrow,
    float* __restrict__ hcol) {
  int b = blockIdx.x;
  int t = threadIdx.x;
  int wave = t >> 6, lane = t & 63;
  int isCol = b >> 10;
  int idx = (b & 1023) * 4 + wave;
  const float* PM = isCol ? colM : rowM;
  const float* PS = isCol ? colS : rowS;
  float M = PM[(size_t)idx * 64 + lane];
  float S = PS[(size_t)idx * 64 + lane];
#pragma unroll
  for (int o = 1; o < 64; o <<= 1) {
    float M2 = __shfl_xor(M, o), S2 = __shfl_xor(S, o);
    float nM = fmaxf(M, M2);
    S = S * __expf(M - nM) + S2 * __expf(M2 - nM);
    M = nM;
  }
  if (lane == 0) {
    float v = M + logf(S) - diag[idx];
    (isCol ? hcol : hrow)[idx] = v;
  }
}

// Kernel 4: final mean in f64: 0.5*(mean(hrow) + mean(hcol)).
__global__ __launch_bounds__(256) void final_kernel(
    const float* __restrict__ hrow, const float* __restrict__ hcol,
    float* __restrict__ out) {
  int t = threadIdx.x;
  double a = 0.0;
  for (int i = t; i < NB; i += 256) {
    a += 0.5 * ((double)hrow[i] + (double)hcol[i]);
  }
#pragma unroll
  for (int o = 32; o > 0; o >>= 1) a += __shfl_xor(a, o);
  __shared__ double sd[4];
  if ((t & 63) == 0) sd[t >> 6] = a;
  __syncthreads();
  if (t == 0) out[0] = (float)(((sd[0] + sd[1]) + (sd[2] + sd[3])) / (double)NB);
}

extern "C" void kernel_launch(void* const* d_in, const int* in_sizes, int n_in,
                              void* d_out, int out_size, void* d_ws, size_t ws_size,
                              hipStream_t stream) {
  const float* v_mean = (const float*)d_in[0];
  const float* v_var = (const float*)d_in[1];
  const float* t_mean = (const float*)d_in[2];
  const float* t_var = (const float*)d_in[3];
  const float* log_temp = (const float*)d_in[4];
  float* out = (float*)d_out;

  char* ws = (char*)d_ws;
  unsigned char* Afp = (unsigned char*)ws;                       // 4 MiB
  unsigned char* Bfp = (unsigned char*)(ws + 4194304);           // 4 MiB
  float* rowM = (float*)(ws + 8388608);                          // 1 MiB each
  float* rowS = rowM + (size_t)NB * 64;
  float* colM = rowS + (size_t)NB * 64;
  float* colS = colM + (size_t)NB * 64;
  float* diag = colS + (size_t)NB * 64;                          // 16 KiB each
  float* hrow = diag + NB;
  float* hcol = hrow + NB;
  float* a_sq = hcol + NB;
  float* b_sq = a_sq + NB;

  prep_kernel<<<8192, 256, 0, stream>>>(v_mean, v_var, t_mean, t_var, Afp, Bfp, a_sq, b_sq);
  gemm_fused_kernel<<<512, 512, 0, stream>>>(Afp, Bfp, a_sq, b_sq, log_temp,
                                             rowM, rowS, colM, colS, diag);
  combine_kernel<<<2048, 256, 0, stream>>>(rowM, rowS, colM, colS, diag, hrow, hcol);
  final_kernel<<<1, 256, 0, stream>>>(hrow, hcol, out);
}